// Round 1
// baseline (19568.814 us; speedup 1.0000x reference)
//
#include <hip/hip_runtime.h>
#include <hip/hip_bf16.h>

typedef __bf16 bf16_t;
typedef __bf16 bf16x8 __attribute__((ext_vector_type(8)));
typedef float f32x4 __attribute__((ext_vector_type(4)));

#define MAX_ITER 10
#define EPSQ 1e-5f

// ---------- helpers ----------

__device__ static inline unsigned short f2bf(float f) {
    union { __bf16 b; unsigned short u; } cvt;
    cvt.b = (__bf16)f;
    return cvt.u;
}

__device__ static inline void gload16(const void* g, void* l) {
    __builtin_amdgcn_global_load_lds((const __attribute__((address_space(1))) void*)g,
                                     (__attribute__((address_space(3))) void*)l,
                                     16, 0, 0);
}

// ---------- gamma = mean(|W|): block partial sums -> f64 atomic ----------

__global__ __launch_bounds__(256) void absum_kernel(const float* __restrict__ W,
                                                    long n4, double* __restrict__ out) {
    double s = 0.0;
    const float4* w4 = (const float4*)W;
    for (long i = (long)blockIdx.x * 256 + threadIdx.x; i < n4; i += (long)gridDim.x * 256) {
        float4 v = w4[i];
        s += (double)(fabsf(v.x) + fabsf(v.y) + fabsf(v.z) + fabsf(v.w));
    }
#pragma unroll
    for (int off = 32; off > 0; off >>= 1) s += __shfl_xor(s, off);
    __shared__ double wsum[4];
    const int wid = threadIdx.x >> 6;
    if ((threadIdx.x & 63) == 0) wsum[wid] = s;
    __syncthreads();
    if (threadIdx.x == 0) atomicAdd(out, wsum[0] + wsum[1] + wsum[2] + wsum[3]);
}

// ---------- ternary weight quant: Wq = clip(round(W/gamma),-1,1) as bf16 ----------

__global__ __launch_bounds__(256) void wquant_kernel(const float* __restrict__ W,
                                                     bf16_t* __restrict__ Q, long n4,
                                                     const double* __restrict__ gsum,
                                                     double invcnt) {
    const float gamma = fmaxf((float)(gsum[0] * invcnt), EPSQ);
    const float4* w4 = (const float4*)W;
    ushort4* q4 = (ushort4*)Q;
    for (long i = (long)blockIdx.x * 256 + threadIdx.x; i < n4; i += (long)gridDim.x * 256) {
        float4 v = w4[i];
        ushort4 o;
        o.x = f2bf(fminf(fmaxf(rintf(v.x / gamma), -1.f), 1.f));
        o.y = f2bf(fminf(fmaxf(rintf(v.y / gamma), -1.f), 1.f));
        o.z = f2bf(fminf(fmaxf(rintf(v.z / gamma), -1.f), 1.f));
        o.w = f2bf(fminf(fmaxf(rintf(v.w / gamma), -1.f), 1.f));
        q4[i] = o;
    }
}

// ---------- per-row (token) absmax int8 activation quant, stored as int-valued bf16 ----------
// L = NV*1024 floats per row; one block (256 thr) per row.

template <int NV>
__global__ __launch_bounds__(256) void actquant_kernel(const float* __restrict__ X,
                                                       bf16_t* __restrict__ Q,
                                                       float* __restrict__ rscale, int L) {
    const int row = blockIdx.x;
    const float4* xr = (const float4*)(X + (size_t)row * L);
    float4 v[NV];
    float am = 0.f;
#pragma unroll
    for (int i = 0; i < NV; i++) {
        v[i] = xr[threadIdx.x + i * 256];
        am = fmaxf(am, fmaxf(fmaxf(fabsf(v[i].x), fabsf(v[i].y)),
                             fmaxf(fabsf(v[i].z), fabsf(v[i].w))));
    }
#pragma unroll
    for (int off = 32; off > 0; off >>= 1) am = fmaxf(am, __shfl_xor(am, off));
    __shared__ float wmax[4];
    const int wid = threadIdx.x >> 6;
    if ((threadIdx.x & 63) == 0) wmax[wid] = am;
    __syncthreads();
    am = fmaxf(fmaxf(wmax[0], wmax[1]), fmaxf(wmax[2], wmax[3]));
    const float scale = 127.f / fmaxf(am, EPSQ);
    if (threadIdx.x == 0) rscale[row] = scale;
    ushort4* qr = (ushort4*)(Q + (size_t)row * L);
#pragma unroll
    for (int i = 0; i < NV; i++) {
        ushort4 o;
        o.x = f2bf(fminf(fmaxf(rintf(v[i].x * scale), -128.f), 127.f));
        o.y = f2bf(fminf(fmaxf(rintf(v[i].y * scale), -128.f), 127.f));
        o.z = f2bf(fminf(fmaxf(rintf(v[i].z * scale), -128.f), 127.f));
        o.w = f2bf(fminf(fmaxf(rintf(v[i].w * scale), -128.f), 127.f));
        qr[threadIdx.x + i * 256] = o;
    }
}

// ---------- NT GEMM: C[m,n] = sum_k A[m,k]*B[n,k]; A,B int-valued bf16, exact f32 acc ----------
// 128x128 tile, BK=32, 4 waves (2x2), per-wave 4x4 frags of 16x16x32 MFMA. m97 structure.
// EPI 0: out = silu(acc*gamma/scale[m] + bias[n])           (f32 h)
// EPI 1: out = xin + (acc*gamma/scale[m] + bias[n]) * euler (f32 x update, in-place ok)

template <int EPI>
__global__ __launch_bounds__(256) void gemm_bt(const bf16_t* __restrict__ A,
                                               const bf16_t* __restrict__ B,
                                               int M, int N, int K,
                                               const float* __restrict__ rowScale,
                                               const double* __restrict__ gsum, double invcnt,
                                               const float* __restrict__ bias,
                                               float* __restrict__ out,
                                               const float* __restrict__ xin, float euler) {
    constexpr int BM = 128, BN = 128, BK = 32;
    __shared__ bf16_t As[BM * BK];
    __shared__ bf16_t Bs[BN * BK];
    const int tid = threadIdx.x;
    const int wid = tid >> 6, lane = tid & 63;
    const int wr = wid >> 1, wc = wid & 1;
    const int Mt = M / BM;
    const int mt = blockIdx.x % Mt, nt = blockIdx.x / Mt;

    // staging: chunk c (16B = 8 bf16): row = c>>2, kpart = (c&3)*8. issue0: c=tid, issue1: c=tid+256
    const int c0 = tid, c1 = tid + 256;
    const bf16_t* Ag0 = A + (size_t)(mt * BM + (c0 >> 2)) * K + (c0 & 3) * 8;
    const bf16_t* Ag1 = A + (size_t)(mt * BM + (c1 >> 2)) * K + (c1 & 3) * 8;
    const bf16_t* Bg0 = B + (size_t)(nt * BN + (c0 >> 2)) * K + (c0 & 3) * 8;
    const bf16_t* Bg1 = B + (size_t)(nt * BN + (c1 >> 2)) * K + (c1 & 3) * 8;
    char* AsW0 = (char*)As + wid * 1024;
    char* AsW1 = (char*)As + 4096 + wid * 1024;
    char* BsW0 = (char*)Bs + wid * 1024;
    char* BsW1 = (char*)Bs + 4096 + wid * 1024;

    // fragment read pointers: A row = wr*64 + (lane&15), k-group = (lane>>4)*8
    const bf16x8* Ard = (const bf16x8*)(As + (wr * 64 + (lane & 15)) * BK + (lane >> 4) * 8);
    const bf16x8* Brd = (const bf16x8*)(Bs + (wc * 64 + (lane & 15)) * BK + (lane >> 4) * 8);

    f32x4 acc[4][4] = {};

    for (int k0 = 0; k0 < K; k0 += BK) {
        gload16(Ag0 + k0, AsW0);
        gload16(Ag1 + k0, AsW1);
        gload16(Bg0 + k0, BsW0);
        gload16(Bg1 + k0, BsW1);
        asm volatile("s_waitcnt vmcnt(0)" ::: "memory");
        __syncthreads();
        bf16x8 af[4], bq[4];
#pragma unroll
        for (int i = 0; i < 4; i++) {
            af[i] = Ard[i * 64];  // +16 rows = 16*32/8 = 64 bf16x8
            bq[i] = Brd[i * 64];
        }
#pragma unroll
        for (int i = 0; i < 4; i++)
#pragma unroll
            for (int j = 0; j < 4; j++)
                acc[i][j] = __builtin_amdgcn_mfma_f32_16x16x32_bf16(af[i], bq[j], acc[i][j], 0, 0, 0);
        __syncthreads();
    }

    // epilogue: C/D layout col = lane&15, row = (lane>>4)*4 + reg  [m89/m91-verified]
    const float gamma = fmaxf((float)(gsum[0] * invcnt), EPSQ);
    const int row0 = mt * BM + wr * 64 + ((lane >> 4) << 2);
    const int col0 = nt * BN + wc * 64 + (lane & 15);
#pragma unroll
    for (int i = 0; i < 4; i++) {
        float fac[4];
#pragma unroll
        for (int r = 0; r < 4; r++) fac[r] = gamma / rowScale[row0 + i * 16 + r];
#pragma unroll
        for (int j = 0; j < 4; j++) {
            const int col = col0 + j * 16;
            const float bv = bias[col];
#pragma unroll
            for (int r = 0; r < 4; r++) {
                const int row = row0 + i * 16 + r;
                const float v = acc[i][j][r] * fac[r] + bv;
                const size_t idx = (size_t)row * N + col;
                if (EPI == 0) {
                    out[idx] = v / (1.f + expf(-v));  // silu
                } else {
                    out[idx] = xin[idx] + v * euler;
                }
            }
        }
    }
}

// ---------- launch ----------

extern "C" void kernel_launch(void* const* d_in, const int* in_sizes, int n_in,
                              void* d_out, int out_size, void* d_ws, size_t ws_size,
                              hipStream_t stream) {
    const float* x0 = (const float*)d_in[0];
    const float* W1 = (const float*)d_in[1];
    const float* b1 = (const float*)d_in[2];
    const float* W2 = (const float*)d_in[3];
    const float* b2 = (const float*)d_in[4];

    const int I = in_sizes[2];           // intermediate = 16384
    const int F = in_sizes[4];           // features = 4096
    const int M = in_sizes[0] / F;       // tokens = 4096
    const long nW = (long)I * F;

    char* ws = (char*)d_ws;
    double* gsum = (double*)ws;          // 2 doubles
    float* xscale = (float*)(ws + 256);
    float* hscale = xscale + M;
    size_t off = 256 + 2 * (size_t)M * 4;
    off = (off + 255) & ~(size_t)255;
    bf16_t* Xq = (bf16_t*)(ws + off);  off += (size_t)M * F * 2;
    bf16_t* Hq = (bf16_t*)(ws + off);  off += (size_t)M * I * 2;
    bf16_t* W1q = (bf16_t*)(ws + off); off += (size_t)nW * 2;
    bf16_t* W2q = (bf16_t*)(ws + off); off += (size_t)nW * 2;
    float* h = (float*)(ws + off);     off += (size_t)M * I * 4;
    (void)ws_size; (void)n_in; (void)out_size;

    float* x = (float*)d_out;
    hipMemcpyAsync(x, x0, (size_t)M * F * 4, hipMemcpyDeviceToDevice, stream);
    hipMemsetAsync(gsum, 0, 16, stream);

    absum_kernel<<<2048, 256, 0, stream>>>(W1, nW / 4, gsum + 0);
    absum_kernel<<<2048, 256, 0, stream>>>(W2, nW / 4, gsum + 1);
    wquant_kernel<<<2048, 256, 0, stream>>>(W1, W1q, nW / 4, gsum + 0, 1.0 / (double)nW);
    wquant_kernel<<<2048, 256, 0, stream>>>(W2, W2q, nW / 4, gsum + 1, 1.0 / (double)nW);

    const float euler = 1.0f / (float)MAX_ITER;
    for (int it = 0; it < MAX_ITER; ++it) {
        actquant_kernel<4><<<M, 256, 0, stream>>>(x, Xq, xscale, F);
        gemm_bt<0><<<(M / 128) * (I / 128), 256, 0, stream>>>(
            Xq, W1q, M, I, F, xscale, gsum + 0, 1.0 / (double)nW, b1, h, nullptr, 0.f);
        actquant_kernel<16><<<M, 256, 0, stream>>>(h, Hq, hscale, I);
        gemm_bt<1><<<(M / 128) * (F / 128), 256, 0, stream>>>(
            Hq, W2q, M, F, I, hscale, gsum + 1, 1.0 / (double)nW, b2, x, x, euler);
    }
}

// Round 2
// 16140.839 us; speedup vs baseline: 1.2124x; 1.2124x over previous
//
#include <hip/hip_runtime.h>
#include <hip/hip_bf16.h>

typedef __bf16 bf16_t;
typedef __bf16 bf16x8 __attribute__((ext_vector_type(8)));
typedef float f32x4 __attribute__((ext_vector_type(4)));

#define MAX_ITER 10
#define EPSQ 1e-5f

// ---------- helpers ----------

__device__ static inline unsigned short f2bf(float f) {
    union { __bf16 b; unsigned short u; } cvt;
    cvt.b = (__bf16)f;
    return cvt.u;
}

__device__ static inline void gload16(const void* g, void* l) {
    __builtin_amdgcn_global_load_lds((const __attribute__((address_space(1))) void*)g,
                                     (__attribute__((address_space(3))) void*)l,
                                     16, 0, 0);
}

// ---------- gamma = mean(|W|): block partial sums -> f64 atomic ----------

__global__ __launch_bounds__(256) void absum_kernel(const float* __restrict__ W,
                                                    long n4, double* __restrict__ out) {
    double s = 0.0;
    const float4* w4 = (const float4*)W;
    for (long i = (long)blockIdx.x * 256 + threadIdx.x; i < n4; i += (long)gridDim.x * 256) {
        float4 v = w4[i];
        s += (double)(fabsf(v.x) + fabsf(v.y) + fabsf(v.z) + fabsf(v.w));
    }
#pragma unroll
    for (int off = 32; off > 0; off >>= 1) s += __shfl_xor(s, off);
    __shared__ double wsum[4];
    const int wid = threadIdx.x >> 6;
    if ((threadIdx.x & 63) == 0) wsum[wid] = s;
    __syncthreads();
    if (threadIdx.x == 0) atomicAdd(out, wsum[0] + wsum[1] + wsum[2] + wsum[3]);
}

// ---------- ternary weight quant: Wq = clip(round(W/gamma),-1,1) as bf16 ----------

__global__ __launch_bounds__(256) void wquant_kernel(const float* __restrict__ W,
                                                     bf16_t* __restrict__ Q, long n4,
                                                     const double* __restrict__ gsum,
                                                     double invcnt) {
    const float gamma = fmaxf((float)(gsum[0] * invcnt), EPSQ);
    const float4* w4 = (const float4*)W;
    ushort4* q4 = (ushort4*)Q;
    for (long i = (long)blockIdx.x * 256 + threadIdx.x; i < n4; i += (long)gridDim.x * 256) {
        float4 v = w4[i];
        ushort4 o;
        o.x = f2bf(fminf(fmaxf(rintf(v.x / gamma), -1.f), 1.f));
        o.y = f2bf(fminf(fmaxf(rintf(v.y / gamma), -1.f), 1.f));
        o.z = f2bf(fminf(fmaxf(rintf(v.z / gamma), -1.f), 1.f));
        o.w = f2bf(fminf(fmaxf(rintf(v.w / gamma), -1.f), 1.f));
        q4[i] = o;
    }
}

// ---------- per-row (token) absmax int8 activation quant, stored as int-valued bf16 ----------

template <int NV>
__global__ __launch_bounds__(256) void actquant_kernel(const float* __restrict__ X,
                                                       bf16_t* __restrict__ Q,
                                                       float* __restrict__ rscale, int L) {
    const int row = blockIdx.x;
    const float4* xr = (const float4*)(X + (size_t)row * L);
    float4 v[NV];
    float am = 0.f;
#pragma unroll
    for (int i = 0; i < NV; i++) {
        v[i] = xr[threadIdx.x + i * 256];
        am = fmaxf(am, fmaxf(fmaxf(fabsf(v[i].x), fabsf(v[i].y)),
                             fmaxf(fabsf(v[i].z), fabsf(v[i].w))));
    }
#pragma unroll
    for (int off = 32; off > 0; off >>= 1) am = fmaxf(am, __shfl_xor(am, off));
    __shared__ float wmax[4];
    const int wid = threadIdx.x >> 6;
    if ((threadIdx.x & 63) == 0) wmax[wid] = am;
    __syncthreads();
    am = fmaxf(fmaxf(wmax[0], wmax[1]), fmaxf(wmax[2], wmax[3]));
    const float scale = 127.f / fmaxf(am, EPSQ);
    if (threadIdx.x == 0) rscale[row] = scale;
    ushort4* qr = (ushort4*)(Q + (size_t)row * L);
#pragma unroll
    for (int i = 0; i < NV; i++) {
        ushort4 o;
        o.x = f2bf(fminf(fmaxf(rintf(v[i].x * scale), -128.f), 127.f));
        o.y = f2bf(fminf(fmaxf(rintf(v[i].y * scale), -128.f), 127.f));
        o.z = f2bf(fminf(fmaxf(rintf(v[i].z * scale), -128.f), 127.f));
        o.w = f2bf(fminf(fmaxf(rintf(v[i].w * scale), -128.f), 127.f));
        qr[threadIdx.x + i * 256] = o;
    }
}

// ---------- NT GEMM: C[m,n] = sum_k A[m,k]*B[n,k]; exact int-valued bf16 MFMA ----------
// 128x128 tile, BK=32, 4 waves (2x2), 4x4 frags of 16x16x32, double-buffered LDS,
// counted vmcnt(4) prefetch (T3 minimum 2-phase), XCD-bijective swizzle + 4x4 supertile.

template <int EPI>
__global__ __launch_bounds__(256) void gemm_bt(const bf16_t* __restrict__ A,
                                               const bf16_t* __restrict__ B,
                                               int M, int N, int K,
                                               const float* __restrict__ rowScale,
                                               const double* __restrict__ gsum, double invcnt,
                                               const float* __restrict__ bias,
                                               float* __restrict__ out,
                                               const float* __restrict__ xin, float euler) {
    constexpr int BM = 128, BN = 128, BK = 32;
    __shared__ bf16_t As[2][BM * BK];
    __shared__ bf16_t Bs[2][BN * BK];
    const int tid = threadIdx.x;
    const int wid = tid >> 6, lane = tid & 63;
    const int wr = wid >> 1, wc = wid & 1;

    // --- XCD-bijective swizzle (m204) + 4x4 supertile for L2 locality ---
    const int nwg = gridDim.x;
    int bid = blockIdx.x;
    const int q = nwg >> 3, r = nwg & 7;
    const int xcd = bid & 7, boff = bid >> 3;
    bid = (xcd < r ? xcd * (q + 1) : r * (q + 1) + (xcd - r) * q) + boff;
    const int Mt = M / BM;
    const int Mt4 = Mt >> 2;                 // Mt % 4 == 0 for our shapes
    const int sup = bid >> 4, wi = bid & 15;
    const int mt = (sup % Mt4) * 4 + (wi & 3);
    const int nt = (sup / Mt4) * 4 + (wi >> 2);

    // staging: chunk c (16B = 8 bf16): row = c>>2, kpart = (c&3)*8; c0 = tid, c1 = tid+256
    const int c0 = tid, c1 = tid + 256;
    const bf16_t* Ag0 = A + (size_t)(mt * BM + (c0 >> 2)) * K + (c0 & 3) * 8;
    const bf16_t* Ag1 = A + (size_t)(mt * BM + (c1 >> 2)) * K + (c1 & 3) * 8;
    const bf16_t* Bg0 = B + (size_t)(nt * BN + (c0 >> 2)) * K + (c0 & 3) * 8;
    const bf16_t* Bg1 = B + (size_t)(nt * BN + (c1 >> 2)) * K + (c1 & 3) * 8;
    char* AsB = (char*)As;                   // 2 buffers x 8192 B each
    char* BsB = (char*)Bs;

    f32x4 acc[4][4] = {};
    const int NT = K / BK;

    auto stage = [&](int buf, int k0) {
        char* ad = AsB + buf * 8192 + wid * 1024;
        char* bd = BsB + buf * 8192 + wid * 1024;
        gload16(Ag0 + k0, ad);
        gload16(Ag1 + k0, ad + 4096);
        gload16(Bg0 + k0, bd);
        gload16(Bg1 + k0, bd + 4096);
    };
    auto compute = [&](int buf) {
        const bf16x8* Ard = (const bf16x8*)(As[buf] + (wr * 64 + (lane & 15)) * BK + (lane >> 4) * 8);
        const bf16x8* Brd = (const bf16x8*)(Bs[buf] + (wc * 64 + (lane & 15)) * BK + (lane >> 4) * 8);
        bf16x8 af[4], bq[4];
#pragma unroll
        for (int i = 0; i < 4; i++) {
            af[i] = Ard[i * 64];             // +16 rows = 64 bf16x8
            bq[i] = Brd[i * 64];
        }
#pragma unroll
        for (int i = 0; i < 4; i++)
#pragma unroll
            for (int j = 0; j < 4; j++)
                acc[i][j] = __builtin_amdgcn_mfma_f32_16x16x32_bf16(af[i], bq[j], acc[i][j], 0, 0, 0);
    };

    // prologue: stage tile 0
    stage(0, 0);
    for (int t = 0; t < NT - 1; ++t) {
        stage((t + 1) & 1, (t + 1) * BK);                 // prefetch next tile
        asm volatile("s_waitcnt vmcnt(4)" ::: "memory");  // tile t resident; next 4 stay in flight
        __builtin_amdgcn_s_barrier();
        __builtin_amdgcn_sched_barrier(0);
        compute(t & 1);
        __builtin_amdgcn_sched_barrier(0);
        __builtin_amdgcn_s_barrier();                     // reads of buf[t&1] done before overwrite
    }
    asm volatile("s_waitcnt vmcnt(0)" ::: "memory");
    __builtin_amdgcn_s_barrier();
    __builtin_amdgcn_sched_barrier(0);
    compute((NT - 1) & 1);

    // epilogue: C/D layout col = lane&15, row = (lane>>4)*4 + reg  [m89/m91-verified]
    const float gamma = fmaxf((float)(gsum[0] * invcnt), EPSQ);
    const int row0 = mt * BM + wr * 64 + ((lane >> 4) << 2);
    const int col0 = nt * BN + wc * 64 + (lane & 15);
#pragma unroll
    for (int i = 0; i < 4; i++) {
        float fac[4];
#pragma unroll
        for (int rr = 0; rr < 4; rr++) fac[rr] = gamma / rowScale[row0 + i * 16 + rr];
#pragma unroll
        for (int j = 0; j < 4; j++) {
            const int col = col0 + j * 16;
            const float bv = bias[col];
#pragma unroll
            for (int rr = 0; rr < 4; rr++) {
                const int row = row0 + i * 16 + rr;
                const float v = acc[i][j][rr] * fac[rr] + bv;
                const size_t idx = (size_t)row * N + col;
                if (EPI == 0) {
                    out[idx] = v / (1.f + expf(-v));      // silu
                } else {
                    out[idx] = xin[idx] + v * euler;
                }
            }
        }
    }
}

// ---------- launch ----------

extern "C" void kernel_launch(void* const* d_in, const int* in_sizes, int n_in,
                              void* d_out, int out_size, void* d_ws, size_t ws_size,
                              hipStream_t stream) {
    const float* x0 = (const float*)d_in[0];
    const float* W1 = (const float*)d_in[1];
    const float* b1 = (const float*)d_in[2];
    const float* W2 = (const float*)d_in[3];
    const float* b2 = (const float*)d_in[4];

    const int I = in_sizes[2];           // intermediate = 16384
    const int F = in_sizes[4];           // features = 4096
    const int M = in_sizes[0] / F;       // tokens = 4096
    const long nW = (long)I * F;

    char* ws = (char*)d_ws;
    double* gsum = (double*)ws;          // 2 doubles
    float* xscale = (float*)(ws + 256);
    float* hscale = xscale + M;
    size_t off = 256 + 2 * (size_t)M * 4;
    off = (off + 255) & ~(size_t)255;
    bf16_t* Xq = (bf16_t*)(ws + off);  off += (size_t)M * F * 2;
    bf16_t* Hq = (bf16_t*)(ws + off);  off += (size_t)M * I * 2;
    bf16_t* W1q = (bf16_t*)(ws + off); off += (size_t)nW * 2;
    bf16_t* W2q = (bf16_t*)(ws + off); off += (size_t)nW * 2;
    float* h = (float*)(ws + off);     off += (size_t)M * I * 4;
    (void)ws_size; (void)n_in; (void)out_size;

    float* x = (float*)d_out;
    hipMemcpyAsync(x, x0, (size_t)M * F * 4, hipMemcpyDeviceToDevice, stream);
    hipMemsetAsync(gsum, 0, 16, stream);

    absum_kernel<<<2048, 256, 0, stream>>>(W1, nW / 4, gsum + 0);
    absum_kernel<<<2048, 256, 0, stream>>>(W2, nW / 4, gsum + 1);
    wquant_kernel<<<2048, 256, 0, stream>>>(W1, W1q, nW / 4, gsum + 0, 1.0 / (double)nW);
    wquant_kernel<<<2048, 256, 0, stream>>>(W2, W2q, nW / 4, gsum + 1, 1.0 / (double)nW);

    const float euler = 1.0f / (float)MAX_ITER;
    for (int it = 0; it < MAX_ITER; ++it) {
        actquant_kernel<4><<<M, 256, 0, stream>>>(x, Xq, xscale, F);
        gemm_bt<0><<<(M / 128) * (I / 128), 256, 0, stream>>>(
            Xq, W1q, M, I, F, xscale, gsum + 0, 1.0 / (double)nW, b1, h, nullptr, 0.f);
        actquant_kernel<16><<<M, 256, 0, stream>>>(h, Hq, hscale, I);
        gemm_bt<1><<<(M / 128) * (F / 128), 256, 0, stream>>>(
            Hq, W2q, M, F, I, hscale, gsum + 1, 1.0 / (double)nW, b2, x, x, euler);
    }
}